// Round 6
// baseline (395.271 us; speedup 1.0000x reference)
//
#include <hip/hip_runtime.h>
#include <hip/hip_bf16.h>

#define NB 64      // batch
#define NT 64      // time
#define NA 64      // action dim
#define NH 1024    // hidden
#define NE 32      // embodiments
#define K2DIM 2048 // 2H

typedef unsigned short bf16_t;
typedef __attribute__((ext_vector_type(8))) short bf16x8;  // 8 bf16 = 4 VGPRs
typedef __attribute__((ext_vector_type(4))) short s16x4;   // 4 bf16 = 2 VGPRs
typedef __attribute__((ext_vector_type(4))) float f32x4;   // MFMA accumulator

__device__ __forceinline__ bf16_t f32_to_bf16(float f) {
    unsigned int u = __float_as_uint(f);
    u = (u + 0x7FFFu + ((u >> 16) & 1u)) >> 16;   // round-to-nearest-even
    return (bf16_t)u;
}
__device__ __forceinline__ unsigned cvt2(float x, float y) {
    unsigned short a = __builtin_bit_cast(unsigned short, __float2bfloat16(x));
    unsigned short b = __builtin_bit_cast(unsigned short, __float2bfloat16(y));
    return (unsigned)a | ((unsigned)b << 16);
}

// ---------------------------------------------------------------------------
// Scheduler: group batches by cat into PAIRS (<=2). groups[g*8] = {cat, nb,
// b0, b1, ...}; nb==0 -> inactive. Deterministic in cat_ids only. (r5, valid)
// ---------------------------------------------------------------------------
__global__ void make_groups(const int* __restrict__ cat_ids,
                            int* __restrict__ groups)
{
    __shared__ int keys[NB], order[NB], catv[NB];
    __shared__ int gcat[NB], gnb[NB], gb[NB][2];
    __shared__ int sng;

    const int tid = threadIdx.x;   // 0..63
    int c = cat_ids[tid];
    catv[tid] = c;
    keys[tid] = c * 64 + tid;      // unique key, stable within cat
    __syncthreads();

    int mykey = keys[tid];
    int rank = 0;
    for (int j = 0; j < NB; ++j) rank += (keys[j] < mykey) ? 1 : 0;
    order[rank] = tid;
    __syncthreads();

    if (tid == 0) {
        int ng = 0, prev = -1, cnt = 2;
        for (int i = 0; i < NB; ++i) {
            int b  = order[i];
            int cb = catv[b];
            if (cb != prev || cnt == 2) {
                gcat[ng] = cb; gnb[ng] = 0; cnt = 0; prev = cb; ++ng;
            }
            gb[ng - 1][cnt] = b;
            ++cnt; gnb[ng - 1] = cnt;
        }
        sng = ng;
    }
    __syncthreads();

    int ng = sng;
    int base = tid * 8;
    if (tid < ng) {
        int nbv = gnb[tid];
        groups[base + 0] = gcat[tid];
        groups[base + 1] = nbv;
        groups[base + 2] = gb[tid][0];
        groups[base + 3] = (nbv > 1) ? gb[tid][1] : gb[tid][0];  // pad w/ b0
        groups[base + 4] = 0; groups[base + 5] = 0;
        groups[base + 6] = 0; groups[base + 7] = 0;
    } else {
        #pragma unroll
        for (int s = 0; s < 8; ++s) groups[base + s] = 0;        // nb = 0
    }
}

// ---------------------------------------------------------------------------
// K1: a_emb = actions @ W1[cat] + b1 (K=64) and sinusoidal PE, fused.
// Writes x = concat(a_emb, pe) as bf16 [B][T][2H]. grid (B, H/64), block 256.
// ---------------------------------------------------------------------------
__global__ __launch_bounds__(256) void k1_embed(
    const float* __restrict__ actions, const float* __restrict__ W1,
    const float* __restrict__ b1, const int* __restrict__ timesteps,
    const int* __restrict__ cat_ids, bf16_t* __restrict__ x)
{
    __shared__ float act[NT][NA];
    __shared__ float pe[64];

    const int b   = blockIdx.x;
    const int c0  = blockIdx.y * 64;
    const int tid = threadIdx.x;
    const int cat = cat_ids[b];
    const float ts = (float)timesteps[b];

    const float* ab = actions + b * (NT * NA);
    #pragma unroll
    for (int p = 0; p < 16; ++p) {
        int idx = tid + p * 256;
        act[idx >> 6][idx & 63] = ab[idx];
    }
    if (tid < 64) {
        const float kfreq = logf(10000.0f) / 512.0f;
        int c = c0 + tid;
        float v;
        if (c < 512) v = sinf(ts * expf(-(float)c * kfreq));
        else         v = cosf(ts * expf(-(float)(c - 512) * kfreq));
        pe[tid] = v;
    }
    __syncthreads();

    const int cc = tid & 63;
    const int c  = c0 + cc;
    const int t0 = tid >> 6;

    float acc[16];
    const float bias = b1[cat * NH + c];
    #pragma unroll
    for (int i = 0; i < 16; ++i) acc[i] = bias;

    const float* Wp = W1 + (size_t)cat * (NA * NH) + c;
    #pragma unroll 8
    for (int k = 0; k < NA; ++k) {
        float w = Wp[(size_t)k * NH];
        #pragma unroll
        for (int i = 0; i < 16; ++i)
            acc[i] = fmaf(act[t0 + 4 * i][k], w, acc[i]);
    }

    bf16_t* xb = x + (size_t)b * (NT * K2DIM);
    const bf16_t pv = f32_to_bf16(pe[cc]);
    #pragma unroll
    for (int i = 0; i < 16; ++i) {
        int t = t0 + 4 * i;
        xb[(size_t)t * K2DIM + c]      = f32_to_bf16(acc[i]);
        xb[(size_t)t * K2DIM + NH + c] = pv;
    }
}

// ---------------------------------------------------------------------------
// Paired MFMA GEMM, deep pipeline. Block: group (<=2 same-cat batches) x 32n.
// grid (32 n, 64 groups). 256 thr = 4 waves = (slot 0..1) x (nf 0..1);
// wave tile 64t x 16n = 4 m-frags, K-chunk 64 (2 x 16x16x32 per m-frag).
// LDS double-buffered 2 x {x: [slot][oct8][t64] 16B units = 16 KB,
//                          W: [slab2][kt8][nt2][4k][16n] bf16 = 4 KB} = 40 KB.
// W global->reg queue depth 2 (wa/wb, unroll-2) => ds_write lead = 2 iters
// (~500+ cyc) covering HBM miss latency; x lead 1 iter (L2-resident).
// B-frags via ds_read_b64_tr_b16 (validated r5 mapping, hi tile offset:256).
// ---------------------------------------------------------------------------
template<int KDIM, bool SWISH, typename OutT>
__global__ __launch_bounds__(256, 3) void gemm_g2p(
    const bf16_t* __restrict__ xin, const float* __restrict__ W,
    const float* __restrict__ bias, const int* __restrict__ groups,
    OutT* __restrict__ out)
{
    __shared__ __align__(128) char lds[2][20480];   // 40 KB

    const int* grp = groups + blockIdx.y * 8;
    const int nb = grp[1];
    if (nb == 0) return;
    const int cat = grp[0];
    const int ba = grp[2];
    const int bb = grp[3];

    const int n0   = blockIdx.x * 32;
    const int tid  = threadIdx.x;
    const int lane = tid & 63;
    const int wv   = tid >> 6;           // 0..3
    const int l15  = lane & 15;
    const int l4   = lane >> 4;
    const int slot = wv >> 1;            // 0..1 (batch slot)
    const int nf   = wv & 1;             // 0..1 (n16 tile)

    constexpr int NCH = KDIM / 64;

    // --- x staging: thread -> (slot, t, k-half), 4 x uint4 = 64 B ---
    const int xs_s = tid >> 7;           // 0..1
    const int xt   = (tid >> 1) & 63;    // 0..63
    const int xoh  = tid & 1;            // 0..1 (k-octets xoh*4 .. +3)
    const bf16_t* xg = xin + ((size_t)(xs_s ? bb : ba) * NT + xt) * KDIM + xoh * 32;
    const int xl = xs_s * 8192 + xoh * 4096 + xt * 16;   // + p_*1024

    // --- W staging: thread -> (k row wk, n-octet), 2 float4 -> 1 b128 write ---
    const int wk   = tid >> 2;           // 0..63
    const int woct = tid & 3;            // 0..3  (n = woct*8)
    const float* wg = W + (size_t)cat * KDIM * NH + (size_t)wk * NH + n0 + woct * 8;
    const int wl = 16384 + (wk >> 5) * 2048 + ((wk & 31) >> 2) * 256
                 + (woct >> 1) * 128 + (wk & 3) * 32 + (woct & 1) * 16;

    // --- accumulators (64t x 16n per wave) ---
    f32x4 acc[4];
    {
        float bv = bias[(size_t)cat * NH + n0 + nf * 16 + l15];
        #pragma unroll
        for (int mf = 0; mf < 4; ++mf) acc[mf] = (f32x4){bv, bv, bv, bv};
    }

    // --- compute-side addresses ---
    const unsigned ldsbase = (unsigned)(unsigned long long)&lds[0][0];
    const unsigned trb0 = ldsbase + 16384u
                        + (unsigned)(l4 * 512 + nf * 128 + l15 * 8);
    const int aoff = slot * 8192 + l4 * 1024 + l15 * 16;  // + ks*4096 + mf*256

    uint4  xr[4];
    float4 wa[2], wb[2];

    auto XLOAD = [&](int c) {
        int i = c < NCH ? c : NCH - 1;           // clamp (harmless re-read)
        const bf16_t* s = xg + (size_t)i * 64;
        #pragma unroll
        for (int p_ = 0; p_ < 4; ++p_) xr[p_] = *(const uint4*)(s + p_ * 8);
    };
    auto XWRITE = [&](char* buf) {
        #pragma unroll
        for (int p_ = 0; p_ < 4; ++p_)
            *(uint4*)(buf + xl + p_ * 1024) = xr[p_];
    };
    auto WLOAD = [&](float4* w, int c) {
        int i = c < NCH ? c : NCH - 1;
        const float* s = wg + (size_t)i * 64 * NH;
        w[0] = *(const float4*)(s);
        w[1] = *(const float4*)(s + 4);
    };
    auto WWRITE = [&](char* buf, const float4* w) {
        uint4 pk;
        pk.x = cvt2(w[0].x, w[0].y);
        pk.y = cvt2(w[0].z, w[0].w);
        pk.z = cvt2(w[1].x, w[1].y);
        pk.w = cvt2(w[1].z, w[1].w);
        *(uint4*)(buf + wl) = pk;
    };
    auto COMPUTE = [&](int p) {
        char* buf = &lds[0][0] + p * 20480;
        unsigned trp = trb0 + (unsigned)(p * 20480);
        #pragma unroll
        for (int ks = 0; ks < 2; ++ks) {
            bf16x8 af[4];
            #pragma unroll
            for (int mf = 0; mf < 4; ++mf)
                af[mf] = *(const bf16x8*)(buf + aoff + ks * 4096 + mf * 256);
            unsigned a = trp + (unsigned)(ks * 2048);
            s16x4 lo, hi;
            asm volatile("ds_read_b64_tr_b16 %0, %1" : "=v"(lo) : "v"(a));
            asm volatile("ds_read_b64_tr_b16 %0, %1 offset:256" : "=v"(hi) : "v"(a));
            bf16x8 bfr = __builtin_shufflevector(lo, hi, 0, 1, 2, 3, 4, 5, 6, 7);
            asm volatile("s_waitcnt lgkmcnt(0)" ::: "memory");
            __builtin_amdgcn_sched_barrier(0);   // rule 18
            #pragma unroll
            for (int mf = 0; mf < 4; ++mf)
                acc[mf] = __builtin_amdgcn_mfma_f32_16x16x32_bf16(
                    af[mf], bfr, acc[mf], 0, 0, 0);
        }
    };

    char* buf0 = &lds[0][0];
    char* buf1 = &lds[0][0] + 20480;

    // prologue: buf0 <- chunk0; queues: wa <- 2, wb <- 1, xr <- 1
    WLOAD(wa, 0); WLOAD(wb, 1); XLOAD(0);
    WWRITE(buf0, wa); XWRITE(buf0);
    WLOAD(wa, 2); XLOAD(1);

    for (int kc = 0; kc < NCH; kc += 2) {
        // even iter: compute buf0 (chunk kc); stage buf1 <- chunk kc+1
        __syncthreads();
        COMPUTE(0);
        WWRITE(buf1, wb); XWRITE(buf1);
        WLOAD(wb, kc + 3); XLOAD(kc + 2);
        // odd iter: compute buf1 (chunk kc+1); stage buf0 <- chunk kc+2
        __syncthreads();
        COMPUTE(1);
        WWRITE(buf0, wa); XWRITE(buf0);
        WLOAD(wa, kc + 4); XLOAD(kc + 3);
    }

    // epilogue: C/D layout col = lane&15, row = (lane>>4)*4 + reg
    if (slot < nb) {
        const int bout = slot ? bb : ba;
        const int col  = n0 + nf * 16 + l15;
        #pragma unroll
        for (int mf = 0; mf < 4; ++mf) {
            #pragma unroll
            for (int r = 0; r < 4; ++r) {
                int trow = mf * 16 + l4 * 4 + r;
                float h = acc[mf][r];
                if (SWISH) h = h / (1.0f + __expf(-h));
                if constexpr (sizeof(OutT) == 2) {
                    out[((size_t)bout * NT + trow) * NH + col] = (OutT)f32_to_bf16(h);
                } else {
                    out[((size_t)bout * NT + trow) * NH + col] = h;
                }
            }
        }
    }
}

extern "C" void kernel_launch(void* const* d_in, const int* in_sizes, int n_in,
                              void* d_out, int out_size, void* d_ws, size_t ws_size,
                              hipStream_t stream) {
    const float* actions   = (const float*)d_in[0];
    const float* W1        = (const float*)d_in[1];
    const float* b1        = (const float*)d_in[2];
    const float* W2        = (const float*)d_in[3];
    const float* b2        = (const float*)d_in[4];
    const float* W3        = (const float*)d_in[5];
    const float* b3        = (const float*)d_in[6];
    const int*   timesteps = (const int*)d_in[7];
    const int*   cat_ids   = (const int*)d_in[8];
    float* out = (float*)d_out;

    // ws: x bf16 [B][T][2H] (16.8 MB), y bf16 [B][T][H] (8.4 MB), groups (2 KB)
    bf16_t* x = (bf16_t*)d_ws;
    bf16_t* y = x + (size_t)NB * NT * K2DIM;
    int* groups = (int*)(y + (size_t)NB * NT * NH);

    make_groups<<<1, 64, 0, stream>>>(cat_ids, groups);
    k1_embed<<<dim3(NB, NH / 64), 256, 0, stream>>>(actions, W1, b1, timesteps, cat_ids, x);
    gemm_g2p<K2DIM, true,  bf16_t><<<dim3(32, 64), 256, 0, stream>>>(x, W2, b2, groups, y);
    gemm_g2p<NH,    false, float ><<<dim3(32, 64), 256, 0, stream>>>(y, W3, b3, groups, out);
}

// Round 7
// 190.454 us; speedup vs baseline: 2.0754x; 2.0754x over previous
//
#include <hip/hip_runtime.h>
#include <hip/hip_bf16.h>

#define NB 64      // batch
#define NT 64      // time
#define NA 64      // action dim
#define NH 1024    // hidden
#define NE 32      // embodiments
#define K2DIM 2048 // 2H

typedef unsigned short bf16_t;
typedef __attribute__((ext_vector_type(8))) short bf16x8;  // 8 bf16 = 4 VGPRs
typedef __attribute__((ext_vector_type(4))) short s16x4;   // 4 bf16 = 2 VGPRs
typedef __attribute__((ext_vector_type(4))) float f32x4;   // MFMA accumulator

__device__ __forceinline__ bf16_t f32_to_bf16(float f) {
    unsigned int u = __float_as_uint(f);
    u = (u + 0x7FFFu + ((u >> 16) & 1u)) >> 16;   // round-to-nearest-even
    return (bf16_t)u;
}
__device__ __forceinline__ unsigned cvt2(float x, float y) {
    unsigned short a = __builtin_bit_cast(unsigned short, __float2bfloat16(x));
    unsigned short b = __builtin_bit_cast(unsigned short, __float2bfloat16(y));
    return (unsigned)a | ((unsigned)b << 16);
}

// ---------------------------------------------------------------------------
// Scheduler: group batches by cat into PAIRS (<=2). groups[g*8] = {cat, nb,
// b0, b1, ...}; nb==0 -> inactive. Deterministic in cat_ids only. (r5, valid)
// ---------------------------------------------------------------------------
__global__ void make_groups(const int* __restrict__ cat_ids,
                            int* __restrict__ groups)
{
    __shared__ int keys[NB], order[NB], catv[NB];
    __shared__ int gcat[NB], gnb[NB], gb[NB][2];
    __shared__ int sng;

    const int tid = threadIdx.x;   // 0..63
    int c = cat_ids[tid];
    catv[tid] = c;
    keys[tid] = c * 64 + tid;      // unique key, stable within cat
    __syncthreads();

    int mykey = keys[tid];
    int rank = 0;
    for (int j = 0; j < NB; ++j) rank += (keys[j] < mykey) ? 1 : 0;
    order[rank] = tid;
    __syncthreads();

    if (tid == 0) {
        int ng = 0, prev = -1, cnt = 2;
        for (int i = 0; i < NB; ++i) {
            int b  = order[i];
            int cb = catv[b];
            if (cb != prev || cnt == 2) {
                gcat[ng] = cb; gnb[ng] = 0; cnt = 0; prev = cb; ++ng;
            }
            gb[ng - 1][cnt] = b;
            ++cnt; gnb[ng - 1] = cnt;
        }
        sng = ng;
    }
    __syncthreads();

    int ng = sng;
    int base = tid * 8;
    if (tid < ng) {
        int nbv = gnb[tid];
        groups[base + 0] = gcat[tid];
        groups[base + 1] = nbv;
        groups[base + 2] = gb[tid][0];
        groups[base + 3] = (nbv > 1) ? gb[tid][1] : gb[tid][0];  // pad w/ b0
        groups[base + 4] = 0; groups[base + 5] = 0;
        groups[base + 6] = 0; groups[base + 7] = 0;
    } else {
        #pragma unroll
        for (int s = 0; s < 8; ++s) groups[base + s] = 0;        // nb = 0
    }
}

// ---------------------------------------------------------------------------
// K1: a_emb = actions @ W1[cat] + b1 (K=64) and sinusoidal PE, fused.
// Writes x = concat(a_emb, pe) as bf16 [B][T][2H]. grid (B, H/64), block 256.
// ---------------------------------------------------------------------------
__global__ __launch_bounds__(256) void k1_embed(
    const float* __restrict__ actions, const float* __restrict__ W1,
    const float* __restrict__ b1, const int* __restrict__ timesteps,
    const int* __restrict__ cat_ids, bf16_t* __restrict__ x)
{
    __shared__ float act[NT][NA];
    __shared__ float pe[64];

    const int b   = blockIdx.x;
    const int c0  = blockIdx.y * 64;
    const int tid = threadIdx.x;
    const int cat = cat_ids[b];
    const float ts = (float)timesteps[b];

    const float* ab = actions + b * (NT * NA);
    #pragma unroll
    for (int p = 0; p < 16; ++p) {
        int idx = tid + p * 256;
        act[idx >> 6][idx & 63] = ab[idx];
    }
    if (tid < 64) {
        const float kfreq = logf(10000.0f) / 512.0f;
        int c = c0 + tid;
        float v;
        if (c < 512) v = sinf(ts * expf(-(float)c * kfreq));
        else         v = cosf(ts * expf(-(float)(c - 512) * kfreq));
        pe[tid] = v;
    }
    __syncthreads();

    const int cc = tid & 63;
    const int c  = c0 + cc;
    const int t0 = tid >> 6;

    float acc[16];
    const float bias = b1[cat * NH + c];
    #pragma unroll
    for (int i = 0; i < 16; ++i) acc[i] = bias;

    const float* Wp = W1 + (size_t)cat * (NA * NH) + c;
    #pragma unroll 8
    for (int k = 0; k < NA; ++k) {
        float w = Wp[(size_t)k * NH];
        #pragma unroll
        for (int i = 0; i < 16; ++i)
            acc[i] = fmaf(act[t0 + 4 * i][k], w, acc[i]);
    }

    bf16_t* xb = x + (size_t)b * (NT * K2DIM);
    const bf16_t pv = f32_to_bf16(pe[cc]);
    #pragma unroll
    for (int i = 0; i < 16; ++i) {
        int t = t0 + 4 * i;
        xb[(size_t)t * K2DIM + c]      = f32_to_bf16(acc[i]);
        xb[(size_t)t * K2DIM + NH + c] = pv;
    }
}

// ---------------------------------------------------------------------------
// Paired MFMA GEMM, lead-2 pipeline, SPILL-FREE (named queue regs only).
// Block: group (<=2 same-cat batches, M=2x64) x 64 n. grid (16 n, 64 groups)
// [x-major so active blocks are a contiguous id prefix]. 512 thr = 8 waves =
// (slot 0..1) x (nf 0..3); wave tile 64t x 16n = 4 m-frags (acc 16 VGPR).
// K-chunk 32, double-buffered LDS 2 x {x 8 KB (conflict-free [slot][oct][t]
// 16B units), W 4 KB subtiled [kt8][nt4][4k][16n]} = 24 KB; ONE barrier per
// chunk. Prefetch lead 2 chunks for BOTH x and W via named regs xrA/xrB/
// wrA/wrB (rule #20: no arrays / no address-taken locals -> no scratch).
// B-frags via ds_read_b64_tr_b16 (byte-validated r5 mapping).
// ---------------------------------------------------------------------------
template<int KDIM, bool SWISH, typename OutT>
__global__ __launch_bounds__(512, 4) void gemm_g2q(
    const bf16_t* __restrict__ xin, const float* __restrict__ W,
    const float* __restrict__ bias, const int* __restrict__ groups,
    OutT* __restrict__ out)
{
    __shared__ __align__(128) char lds[2][12288];   // 24 KB

    const int* grp = groups + blockIdx.y * 8;
    const int nb = grp[1];
    if (nb == 0) return;
    const int cat = grp[0];
    const int ba = grp[2];
    const int bb = grp[3];

    const int n0   = blockIdx.x * 64;
    const int tid  = threadIdx.x;
    const int lane = tid & 63;
    const int wv   = tid >> 6;           // 0..7
    const int l15  = lane & 15;
    const int l4   = lane >> 4;
    const int slot = wv >> 2;            // 0..1  (batch slot)
    const int nf   = wv & 3;             // 0..3  (n16 tile)

    constexpr int NCH = KDIM / 32;

    // --- x staging: thread -> (slot, t, k-octet), one uint4 ---
    const int xs_s = tid >> 8;           // 0..1
    const int xid  = tid & 255;
    const int xt   = xid >> 2;           // 0..63
    const int xoct = xid & 3;            // 0..3
    const bf16_t* xg = xin + ((size_t)(xs_s ? bb : ba) * NT + xt) * KDIM + xoct * 8;
    const int xl = xs_s * 4096 + xoct * 1024 + xt * 16;

    // --- W staging: thread -> (k row, n-quad), float4 -> uint2 b64 write ---
    const int wk  = tid >> 4;            // 0..31
    const int wq4 = tid & 15;            // 0..15 (n = wq4*4)
    const float* wg = W + (size_t)cat * KDIM * NH + (size_t)wk * NH + n0 + wq4 * 4;
    const int wl = 8192 + ((wk >> 2) * 4 + (wq4 >> 2)) * 128
                        + (wk & 3) * 32 + (wq4 & 3) * 8;

    // --- accumulators (64t x 16n per wave) ---
    f32x4 acc[4];
    {
        float bv = bias[(size_t)cat * NH + n0 + nf * 16 + l15];
        #pragma unroll
        for (int mf = 0; mf < 4; ++mf) acc[mf] = (f32x4){bv, bv, bv, bv};
    }

    // --- compute-side addresses ---
    const unsigned ldsbase = (unsigned)(unsigned long long)&lds[0][0];
    const unsigned trb = ldsbase + 8192u + (unsigned)(l4 * 1024 + nf * 128 + l15 * 8);
    const int aoff = slot * 4096 + l4 * 1024 + l15 * 16;

    // --- named prefetch queue (NO arrays, NO address-taken locals) ---
    uint4  xrA, xrB;
    float4 wrA, wrB;

#define XLD(dst, c) do { int i_ = (c) < NCH ? (c) : NCH - 1;                 \
        dst = *(const uint4*)(xg + (size_t)i_ * 32); } while (0)
#define WLD(dst, c) do { int i_ = (c) < NCH ? (c) : NCH - 1;                 \
        dst = *(const float4*)(wg + (size_t)i_ * 32 * NH); } while (0)
#define STG(p, xr_, wr_) do {                                                \
        char* b_ = &lds[p][0];                                               \
        *(uint4*)(b_ + xl) = xr_;                                            \
        uint2 pk_; pk_.x = cvt2(wr_.x, wr_.y); pk_.y = cvt2(wr_.z, wr_.w);   \
        *(uint2*)(b_ + wl) = pk_; } while (0)

    auto COMPUTE = [&](int p) {
        const char* b_ = &lds[p][0];
        bf16x8 af0 = *(const bf16x8*)(b_ + aoff);
        bf16x8 af1 = *(const bf16x8*)(b_ + aoff + 256);
        bf16x8 af2 = *(const bf16x8*)(b_ + aoff + 512);
        bf16x8 af3 = *(const bf16x8*)(b_ + aoff + 768);
        unsigned a = trb + (unsigned)(p * 12288);
        s16x4 lo, hi;
        asm volatile("ds_read_b64_tr_b16 %0, %1" : "=v"(lo) : "v"(a));
        asm volatile("ds_read_b64_tr_b16 %0, %1 offset:512" : "=v"(hi) : "v"(a));
        bf16x8 bfr = __builtin_shufflevector(lo, hi, 0, 1, 2, 3, 4, 5, 6, 7);
        asm volatile("s_waitcnt lgkmcnt(0)" ::: "memory");
        __builtin_amdgcn_sched_barrier(0);   // rule 18
        acc[0] = __builtin_amdgcn_mfma_f32_16x16x32_bf16(af0, bfr, acc[0], 0, 0, 0);
        acc[1] = __builtin_amdgcn_mfma_f32_16x16x32_bf16(af1, bfr, acc[1], 0, 0, 0);
        acc[2] = __builtin_amdgcn_mfma_f32_16x16x32_bf16(af2, bfr, acc[2], 0, 0, 0);
        acc[3] = __builtin_amdgcn_mfma_f32_16x16x32_bf16(af3, bfr, acc[3], 0, 0, 0);
    };

    // prologue: stage chunk0 into buf0; queue A<-chunk2, B<-chunk1
    XLD(xrA, 0); WLD(wrA, 0);
    STG(0, xrA, wrA);
    XLD(xrB, 1); WLD(wrB, 1);
    XLD(xrA, 2); WLD(wrA, 2);

    // steady state: half-iter i computes buf[i&1] (chunk i), stages chunk i+1
    // into the other buffer from the reg set loaded 2 chunks earlier.
    for (int kc = 0; kc < NCH; kc += 2) {
        __syncthreads();
        COMPUTE(0);                        // chunk kc
        STG(1, xrB, wrB);                  // chunk kc+1 -> buf1
        XLD(xrB, kc + 3); WLD(wrB, kc + 3);
        __syncthreads();
        COMPUTE(1);                        // chunk kc+1
        STG(0, xrA, wrA);                  // chunk kc+2 -> buf0
        XLD(xrA, kc + 4); WLD(wrA, kc + 4);
    }
#undef XLD
#undef WLD
#undef STG

    // epilogue: C/D layout col = lane&15, row = (lane>>4)*4 + reg
    if (slot < nb) {
        const int bout = slot ? bb : ba;
        const int col  = n0 + nf * 16 + l15;
        #pragma unroll
        for (int mf = 0; mf < 4; ++mf) {
            #pragma unroll
            for (int r = 0; r < 4; ++r) {
                int trow = mf * 16 + l4 * 4 + r;
                float h = acc[mf][r];
                if (SWISH) h = h / (1.0f + __expf(-h));
                if constexpr (sizeof(OutT) == 2) {
                    out[((size_t)bout * NT + trow) * NH + col] = (OutT)f32_to_bf16(h);
                } else {
                    out[((size_t)bout * NT + trow) * NH + col] = h;
                }
            }
        }
    }
}

extern "C" void kernel_launch(void* const* d_in, const int* in_sizes, int n_in,
                              void* d_out, int out_size, void* d_ws, size_t ws_size,
                              hipStream_t stream) {
    const float* actions   = (const float*)d_in[0];
    const float* W1        = (const float*)d_in[1];
    const float* b1        = (const float*)d_in[2];
    const float* W2        = (const float*)d_in[3];
    const float* b2        = (const float*)d_in[4];
    const float* W3        = (const float*)d_in[5];
    const float* b3        = (const float*)d_in[6];
    const int*   timesteps = (const int*)d_in[7];
    const int*   cat_ids   = (const int*)d_in[8];
    float* out = (float*)d_out;

    // ws: x bf16 [B][T][2H] (16.8 MB), y bf16 [B][T][H] (8.4 MB), groups (2 KB)
    bf16_t* x = (bf16_t*)d_ws;
    bf16_t* y = x + (size_t)NB * NT * K2DIM;
    int* groups = (int*)(y + (size_t)NB * NT * NH);

    make_groups<<<1, 64, 0, stream>>>(cat_ids, groups);
    k1_embed<<<dim3(NB, NH / 64), 256, 0, stream>>>(actions, W1, b1, timesteps, cat_ids, x);
    gemm_g2q<K2DIM, true,  bf16_t><<<dim3(16, 64), 512, 0, stream>>>(x, W2, b2, groups, y);
    gemm_g2q<NH,    false, float ><<<dim3(16, 64), 512, 0, stream>>>(y, W3, b3, groups, out);
}

// Round 8
// 173.050 us; speedup vs baseline: 2.2841x; 1.1006x over previous
//
#include <hip/hip_runtime.h>
#include <hip/hip_bf16.h>

#define NB 64      // batch
#define NT 64      // time
#define NA 64      // action dim
#define NH 1024    // hidden
#define NE 32      // embodiments
#define K2DIM 2048 // 2H

typedef unsigned short bf16_t;
typedef __attribute__((ext_vector_type(8))) short bf16x8;  // 8 bf16 = 4 VGPRs
typedef __attribute__((ext_vector_type(4))) short s16x4;   // 4 bf16 = 2 VGPRs
typedef __attribute__((ext_vector_type(4))) float f32x4;   // MFMA accumulator

#define AS1 __attribute__((address_space(1)))
#define AS3 __attribute__((address_space(3)))

__device__ __forceinline__ bf16_t f32_to_bf16(float f) {
    unsigned int u = __float_as_uint(f);
    u = (u + 0x7FFFu + ((u >> 16) & 1u)) >> 16;   // round-to-nearest-even
    return (bf16_t)u;
}
__device__ __forceinline__ unsigned cvt2(float x, float y) {
    unsigned short a = __builtin_bit_cast(unsigned short, __float2bfloat16(x));
    unsigned short b = __builtin_bit_cast(unsigned short, __float2bfloat16(y));
    return (unsigned)a | ((unsigned)b << 16);
}
// async global->LDS, 16B per lane, wave-uniform LDS base (m03/m97)
__device__ __forceinline__ void gload_lds16(const void* g, void* l) {
    __builtin_amdgcn_global_load_lds((const AS1 void*)g, (AS3 void*)l, 16, 0, 0);
}

// ---------------------------------------------------------------------------
// K1: a_emb = actions @ W1[cat] + b1 (K=64) and sinusoidal PE, fused.
// Writes x = concat(a_emb, pe) as bf16 [B][T][2H]. grid (B, H/64), block 256.
// ---------------------------------------------------------------------------
__global__ __launch_bounds__(256) void k1_embed(
    const float* __restrict__ actions, const float* __restrict__ W1,
    const float* __restrict__ b1, const int* __restrict__ timesteps,
    const int* __restrict__ cat_ids, bf16_t* __restrict__ x)
{
    __shared__ float act[NT][NA];
    __shared__ float pe[64];

    const int b   = blockIdx.x;
    const int c0  = blockIdx.y * 64;
    const int tid = threadIdx.x;
    const int cat = cat_ids[b];
    const float ts = (float)timesteps[b];

    const float* ab = actions + b * (NT * NA);
    #pragma unroll
    for (int p = 0; p < 16; ++p) {
        int idx = tid + p * 256;
        act[idx >> 6][idx & 63] = ab[idx];
    }
    if (tid < 64) {
        const float kfreq = logf(10000.0f) / 512.0f;
        int c = c0 + tid;
        float v;
        if (c < 512) v = sinf(ts * expf(-(float)c * kfreq));
        else         v = cosf(ts * expf(-(float)(c - 512) * kfreq));
        pe[tid] = v;
    }
    __syncthreads();

    const int cc = tid & 63;
    const int c  = c0 + cc;
    const int t0 = tid >> 6;

    float acc[16];
    const float bias = b1[cat * NH + c];
    #pragma unroll
    for (int i = 0; i < 16; ++i) acc[i] = bias;

    const float* Wp = W1 + (size_t)cat * (NA * NH) + c;
    #pragma unroll 8
    for (int k = 0; k < NA; ++k) {
        float w = Wp[(size_t)k * NH];
        #pragma unroll
        for (int i = 0; i < 16; ++i)
            acc[i] = fmaf(act[t0 + 4 * i][k], w, acc[i]);
    }

    bf16_t* xb = x + (size_t)b * (NT * K2DIM);
    const bf16_t pv = f32_to_bf16(pe[cc]);
    #pragma unroll
    for (int i = 0; i < 16; ++i) {
        int t = t0 + 4 * i;
        xb[(size_t)t * K2DIM + c]      = f32_to_bf16(acc[i]);
        xb[(size_t)t * K2DIM + NH + c] = pv;
    }
}

// ---------------------------------------------------------------------------
// Counted-vmcnt pipelined MFMA GEMM (T3/T4 adapted).
// Block (b, 128n); grid (8, 64) -> 512 blocks = exactly 2/CU, all resident.
// 512 thr = 8 waves (wm 0..1 x wn 0..3); wave tile 32t x 32n = 2x2 frags.
// K-chunk 64. LDS 2 x 24 KB: x [64t][64k] XOR-swizzled (staged by
// global_load_lds w/ pre-swizzled per-lane SOURCE - rule 21) + W 16 KB
// tr-subtiled (byte-identical to the r3-validated layout).
// RAW s_barrier + manual counted waits: vmcnt(4) per chunk (never 0) so the
// 2-chunk-deep named-reg W queue and the x gload survive across barriers.
// Per chunk: barrier; XL(c+1); WST(c+1) from 2-chunk-old regs; WLD(c+3);
// COMPUTE(c) [ds reads, lgkmcnt(0), sched_barrier, 8 MFMA]; vmcnt(4).
// ---------------------------------------------------------------------------
template<int KDIM, bool SWISH, typename OutT>
__global__ __launch_bounds__(512, 4) void gemm_pipe(
    const bf16_t* __restrict__ xin, const float* __restrict__ W,
    const float* __restrict__ bias, const int* __restrict__ cat_ids,
    OutT* __restrict__ out)
{
    __shared__ __align__(128) char lds[2][24576];   // 48 KB

    const int b    = blockIdx.y;
    const int n0   = blockIdx.x * 128;
    const int tid  = threadIdx.x;
    const int lane = tid & 63;
    const int wv   = tid >> 6;          // 0..7
    const int l15  = lane & 15;
    const int l4   = lane >> 4;
    const int wm   = wv >> 2;           // 0..1  m half (32t)
    const int wn   = wv & 3;            // 0..3  n quarter (32n)
    const int cat  = cat_ids[b];

    constexpr int NCH = KDIM / 64;

    // --- x staging: slot = tid (16B). t = tid>>3, j = tid&7; source k-octet
    // pre-swizzled k8 = j ^ (t&7) so linear LDS == swizzled layout (rule 21).
    const int xt = tid >> 3;
    const int xj = tid & 7;
    const bf16_t* xg = xin + ((size_t)b * NT + xt) * KDIM + ((xj ^ (xt & 7)) * 8);

    // --- W staging: k = tid>>3 (0..63), o2 = tid&7 (n16-tile), octs o2*2+{0,1}
    const int wk  = tid >> 3;
    const int wo2 = tid & 7;
    const float* wg = W + (size_t)cat * KDIM * NH + (size_t)wk * NH + n0 + wo2 * 16;
    const int wloff = 8192 + ((wk >> 2) * 8 + wo2) * 128 + (wk & 3) * 32;

    // --- accumulators: wave (wm,wn), frags [m][nf] ---
    f32x4 acc[2][2];
    #pragma unroll
    for (int nf = 0; nf < 2; ++nf) {
        float bv = bias[(size_t)cat * NH + n0 + wn * 32 + nf * 16 + l15];
        acc[0][nf] = (f32x4){bv, bv, bv, bv};
        acc[1][nf] = acc[0][nf];
    }

    const unsigned lbase = (unsigned)(unsigned long long)&lds[0][0];
    const unsigned trb   = lbase + 8192u
                         + (unsigned)(l4 * 2048 + l15 * 8 + wn * 2 * 128);

    // named 2-deep W queue (rule #20: no arrays, no address-taken locals)
    float4 a0, a1, a2, a3, b0, b1, b2, b3;

#define XL(c) do { int i_ = (c) < NCH ? (c) : NCH - 1;                        \
        gload_lds16(xg + (size_t)i_ * 64,                                     \
                    &lds[0][0] + ((c) & 1) * 24576 + wv * 1024); } while (0)
#define WLD(d0,d1,d2,d3,c) do { int i_ = (c) < NCH ? (c) : NCH - 1;           \
        const float* s_ = wg + (size_t)i_ * 64 * NH;                          \
        d0 = *(const float4*)(s_);     d1 = *(const float4*)(s_ + 4);         \
        d2 = *(const float4*)(s_ + 8); d3 = *(const float4*)(s_ + 12); } while (0)
#define WST(p_, s0,s1,s2,s3) do {                                             \
        char* bp_ = &lds[0][0] + (p_) * 24576;                                \
        uint4 k0_, k1_;                                                       \
        k0_.x = cvt2(s0.x, s0.y); k0_.y = cvt2(s0.z, s0.w);                   \
        k0_.z = cvt2(s1.x, s1.y); k0_.w = cvt2(s1.z, s1.w);                   \
        k1_.x = cvt2(s2.x, s2.y); k1_.y = cvt2(s2.z, s2.w);                   \
        k1_.z = cvt2(s3.x, s3.y); k1_.w = cvt2(s3.z, s3.w);                   \
        *(uint4*)(bp_ + wloff)      = k0_;                                    \
        *(uint4*)(bp_ + wloff + 16) = k1_; } while (0)

    auto COMPUTE = [&](int p) {
        const char* bp = &lds[0][0] + p * 24576;
        bf16x8 af[2][2];
        s16x4  lo[2][2], hi[2][2];
        #pragma unroll
        for (int ks = 0; ks < 2; ++ks) {
            #pragma unroll
            for (int m = 0; m < 2; ++m) {
                int row = wm * 32 + m * 16 + l15;
                af[ks][m] = *(const bf16x8*)(bp + row * 128
                              + (((ks * 4 + l4) ^ (row & 7)) * 16));
            }
            #pragma unroll
            for (int nf = 0; nf < 2; ++nf) {
                unsigned a = trb + (unsigned)(p * 24576 + ks * 8192 + nf * 128);
                asm volatile("ds_read_b64_tr_b16 %0, %1" : "=v"(lo[ks][nf]) : "v"(a));
                asm volatile("ds_read_b64_tr_b16 %0, %1 offset:1024" : "=v"(hi[ks][nf]) : "v"(a));
            }
        }
        asm volatile("s_waitcnt lgkmcnt(0)" ::: "memory");
        __builtin_amdgcn_sched_barrier(0);   // rule 18
        #pragma unroll
        for (int ks = 0; ks < 2; ++ks)
            #pragma unroll
            for (int m = 0; m < 2; ++m)
                #pragma unroll
                for (int nf = 0; nf < 2; ++nf) {
                    bf16x8 bfr = __builtin_shufflevector(
                        lo[ks][nf], hi[ks][nf], 0, 1, 2, 3, 4, 5, 6, 7);
                    acc[m][nf] = __builtin_amdgcn_mfma_f32_16x16x32_bf16(
                        af[ks][m], bfr, acc[m][nf], 0, 0, 0);
                }
    };

    // prologue: buf0 <- chunk0; queue A<-chunk2 (after staging 0), B<-chunk1
    XL(0);
    __builtin_amdgcn_sched_barrier(0);
    WLD(a0, a1, a2, a3, 0);
    WLD(b0, b1, b2, b3, 1);
    WST(0, a0, a1, a2, a3);          // compiler: counted vmcnt (drains XL0+WL0)
    WLD(a0, a1, a2, a3, 2);
    asm volatile("s_waitcnt lgkmcnt(0)" ::: "memory");

    for (int kc = 0; kc < NCH; kc += 2) {
        // chunk kc (even, buf0): stage kc+1 -> buf1
        __builtin_amdgcn_s_barrier();
        XL(kc + 1);
        __builtin_amdgcn_sched_barrier(0);
        WST(1, b0, b1, b2, b3);      // compiler inserts counted vmcnt(5)
        WLD(b0, b1, b2, b3, kc + 3);
        COMPUTE(0);
        asm volatile("s_waitcnt vmcnt(4)" ::: "memory");  // XL(kc+1) done; WLD stays
        // chunk kc+1 (odd, buf1): stage kc+2 -> buf0
        __builtin_amdgcn_s_barrier();
        XL(kc + 2);
        __builtin_amdgcn_sched_barrier(0);
        WST(0, a0, a1, a2, a3);
        WLD(a0, a1, a2, a3, kc + 4);
        COMPUTE(1);
        asm volatile("s_waitcnt vmcnt(4)" ::: "memory");
    }
#undef XL
#undef WLD
#undef WST

    // epilogue: C/D layout col = lane&15, row = (lane>>4)*4 + reg  [m89/m91]
    #pragma unroll
    for (int m = 0; m < 2; ++m) {
        #pragma unroll
        for (int nf = 0; nf < 2; ++nf) {
            int col = n0 + wn * 32 + nf * 16 + l15;
            #pragma unroll
            for (int r = 0; r < 4; ++r) {
                int row = wm * 32 + m * 16 + l4 * 4 + r;
                float h = acc[m][nf][r];
                if (SWISH) h = h / (1.0f + __expf(-h));
                if constexpr (sizeof(OutT) == 2) {
                    out[((size_t)b * NT + row) * NH + col] = (OutT)f32_to_bf16(h);
                } else {
                    out[((size_t)b * NT + row) * NH + col] = h;
                }
            }
        }
    }
}

extern "C" void kernel_launch(void* const* d_in, const int* in_sizes, int n_in,
                              void* d_out, int out_size, void* d_ws, size_t ws_size,
                              hipStream_t stream) {
    const float* actions   = (const float*)d_in[0];
    const float* W1        = (const float*)d_in[1];
    const float* b1        = (const float*)d_in[2];
    const float* W2        = (const float*)d_in[3];
    const float* b2        = (const float*)d_in[4];
    const float* W3        = (const float*)d_in[5];
    const float* b3        = (const float*)d_in[6];
    const int*   timesteps = (const int*)d_in[7];
    const int*   cat_ids   = (const int*)d_in[8];
    float* out = (float*)d_out;

    // ws: x bf16 [B][T][2H] (16.8 MB) then y bf16 [B][T][H] (8.4 MB)
    bf16_t* x = (bf16_t*)d_ws;
    bf16_t* y = x + (size_t)NB * NT * K2DIM;

    k1_embed<<<dim3(NB, NH / 64), 256, 0, stream>>>(actions, W1, b1, timesteps, cat_ids, x);
    gemm_pipe<K2DIM, true,  bf16_t><<<dim3(8, 64), 512, 0, stream>>>(x, W2, b2, cat_ids, y);
    gemm_pipe<NH,    false, float ><<<dim3(8, 64), 512, 0, stream>>>(y, W3, b3, cat_ids, out);
}